// Round 19
// baseline (434.856 us; speedup 1.0000x reference)
//
#include <hip/hip_runtime.h>
#include <hip/hip_fp16.h>

#define G_ 512
#define B_ 64
#define I_ 32
#define H_ 64
#define NGATE 256  // 4*H
#define GSPLIT 384 // scan phase split: A = [0,384), B = [384,512)

typedef _Float16 half8 __attribute__((ext_vector_type(8)));
typedef _Float16 h4 __attribute__((ext_vector_type(4)));
typedef _Float16 h2 __attribute__((ext_vector_type(2)));
typedef float f32x4 __attribute__((ext_vector_type(4)));

#if __has_builtin(__builtin_amdgcn_fdot2)
#define FDOT2(a, b, c) __builtin_amdgcn_fdot2((a), (b), (c), false)
#else
#define FDOT2(a, b, c) ((c) + (float)(a)[0] * (float)(b)[0] + (float)(a)[1] * (float)(b)[1])
#endif

__device__ __forceinline__ float sigf(float x) {
  return 1.0f / (1.0f + __expf(-x));
}
__device__ __forceinline__ float tanh_fast(float x) {
  x = fminf(fmaxf(x, -15.0f), 15.0f);
  float e = __expf(2.0f * x);
  return (e - 1.0f) / (e + 1.0f);
}

// async global->LDS, 16 B per lane: LDS dest = wave-uniform base, global src
// per-lane (base + lane*16B).
__device__ __forceinline__ void gload_lds16(const _Float16* g, _Float16* l) {
  __builtin_amdgcn_global_load_lds(
      (const __attribute__((address_space(1))) void*)g,
      (__attribute__((address_space(3))) void*)l, 16, 0, 0);
}

// ---------------- K1: xproj[b][g][col*4+q]  (coalesced; scan reads one h4/lane)
__global__ __launch_bounds__(256) void k_xproj(
    const float* __restrict__ input, const float* __restrict__ W_ih,
    const float* __restrict__ b_ih, const float* __restrict__ b_hh,
    _Float16* __restrict__ xproj) {
  const int g = blockIdx.x;
  const int t = threadIdx.x;
  const int col = t >> 2;
  const int q = t & 3;
  const int row = q * H_ + col;  // gate-row in torch i,f,g,o order
  __shared__ alignas(16) float inp[B_ * I_];
  const float* ing = input + (size_t)g * (B_ * I_);
#pragma unroll
  for (int u = 0; u < (B_ * I_) / 256; ++u) inp[u * 256 + t] = ing[u * 256 + t];
  float w[I_];
#pragma unroll
  for (int k = 0; k < I_; k += 4) {
    f32x4 v = *(const f32x4*)(W_ih + (size_t)row * I_ + k);
    w[k] = v[0]; w[k + 1] = v[1]; w[k + 2] = v[2]; w[k + 3] = v[3];
  }
  const float bias = b_ih[row] + b_hh[row];
  __syncthreads();
  for (int b = 0; b < B_; ++b) {
    float a0 = bias, a1 = 0.f, a2 = 0.f, a3 = 0.f;
#pragma unroll
    for (int k = 0; k < I_; k += 4) {
      f32x4 iv = *(const f32x4*)&inp[b * I_ + k];
      a0 += iv[0] * w[k]; a1 += iv[1] * w[k + 1];
      a2 += iv[2] * w[k + 2]; a3 += iv[3] * w[k + 3];
    }
    xproj[((size_t)b * G_ + g) * NGATE + t] = (_Float16)((a0 + a1) + (a2 + a3));
  }
}

// ---------------- R5-proven scan body over a g-range [GB, GE).
// FIRST: init from h0/c0 and save c-state at the end; else resume from
// cstate + hs row GB-1. Inner loop byte-identical to the proven R5 code.
template <int GB, int GE, bool FIRST>
__device__ __forceinline__ void scan_range(
    int b, int j, const _Float16* __restrict__ xproj,
    const float* __restrict__ h0, const float* __restrict__ c0,
    float* __restrict__ cstate, const float* __restrict__ W_hh,
    _Float16* __restrict__ hs, _Float16* hsh) {
  h2 w[4][32];
#pragma unroll
  for (int q = 0; q < 4; ++q) {
    const f32x4* wr = (const f32x4*)(W_hh + (size_t)(q * H_ + j) * H_);
#pragma unroll
    for (int kk = 0; kk < 16; ++kk) {
      f32x4 v = wr[kk];
      h2 t0, t1;
      t0[0] = (_Float16)v[0]; t0[1] = (_Float16)v[1];
      t1[0] = (_Float16)v[2]; t1[1] = (_Float16)v[3];
      w[q][2 * kk] = t0;
      w[q][2 * kk + 1] = t1;
    }
  }
  float c;
  if (FIRST) {
    c = c0[b * H_ + j];
    hsh[j] = (_Float16)h0[b * H_ + j];
  } else {
    c = cstate[b * H_ + j];
    hsh[j] = hs[(size_t)b * (G_ * H_) + (size_t)(GB - 1) * H_ + j];
  }

  const h4* xrow = (const h4*)(xproj + (size_t)b * G_ * NGATE) + j;
  h4 p[8];
#pragma unroll
  for (int d = 0; d < 8; ++d) p[d] = xrow[(size_t)(GB + d) * 64];

  _Float16* hrow = hs + (size_t)b * (G_ * H_) + j;

  for (int g0 = GB; g0 < GE; g0 += 8) {
#pragma unroll
    for (int d = 0; d < 8; ++d) {
      const int g = g0 + d;
      float a[4], a2[4];
#pragma unroll
      for (int q = 0; q < 4; ++q) { a[q] = (float)p[d][q]; a2[q] = 0.0f; }
      const f32x4* hp4 = (const f32x4*)hsh;
#pragma unroll
      for (int k4 = 0; k4 < 4; ++k4) {
        f32x4 hv4 = hp4[k4];
#pragma unroll
        for (int t = 0; t < 4; ++t) {
          h2 hv = __builtin_bit_cast(h2, hv4[t]);
#pragma unroll
          for (int q = 0; q < 4; ++q) a[q] = FDOT2(hv, w[q][k4 * 4 + t], a[q]);
        }
      }
#pragma unroll
      for (int k4 = 4; k4 < 8; ++k4) {
        f32x4 hv4 = hp4[k4];
#pragma unroll
        for (int t = 0; t < 4; ++t) {
          h2 hv = __builtin_bit_cast(h2, hv4[t]);
#pragma unroll
          for (int q = 0; q < 4; ++q) a2[q] = FDOT2(hv, w[q][k4 * 4 + t], a2[q]);
        }
      }
#pragma unroll
      for (int q = 0; q < 4; ++q) a[q] += a2[q];

      float ig = sigf(a[0]);
      float fg = sigf(a[1]);
      float gg = tanh_fast(a[2]);
      float og = sigf(a[3]);
      c = fg * c + ig * gg;
      float hh = og * tanh_fast(c);
      _Float16 hf = (_Float16)hh;
      hsh[j] = hf;
      hrow[(size_t)g * H_] = hf;
      if (g + 8 < G_) p[d] = xrow[(size_t)(g + 8) * 64];
    }
  }
  if (FIRST) cstate[b * H_ + j] = c;
}

// ---------------- f32 -> f16 convert into TILE-LINEAR layout, KWT=64 (R15-proven).
template <int N, int K>
__device__ __forceinline__ void conv_tiled(
    const float* __restrict__ src, _Float16* __restrict__ dst,
    int gtid, int gstride) {
  constexpr int KWT = 64;
  constexpr int TILEH = 64 * KWT;  // halves per tile (4096)
  for (int i = gtid; i < N * (K / 8); i += gstride) {
    const int n = i / (K / 8);
    const int k8 = i % (K / 8);
    const f32x4* s = (const f32x4*)(src + (size_t)n * K + (size_t)k8 * 8);
    f32x4 v0 = s[0];
    f32x4 v1 = s[1];
    half8 h;
    h[0] = (_Float16)v0[0]; h[1] = (_Float16)v0[1];
    h[2] = (_Float16)v0[2]; h[3] = (_Float16)v0[3];
    h[4] = (_Float16)v1[0]; h[5] = (_Float16)v1[1];
    h[6] = (_Float16)v1[2]; h[7] = (_Float16)v1[3];
    const int nt = n >> 6, rr = n & 63;
    const int ksg = k8 >> 3;         // k/64
    const int kk8 = k8 & 7;          // (k%64)/8
    const size_t tile_id = (size_t)nt * (K / KWT) + ksg;
    int byte = rr * (KWT * 2) + ((kk8 * 16) ^ ((rr & 7) << 4));
    *(half8*)((char*)(dst + tile_id * TILEH) + byte) = h;
  }
}

#define NCONV 2048

// ---------------- GEMM core (R15-proven pipeline), callable from fused kernels.
template <int N, int K, int KC>
__device__ __forceinline__ void gemm_core(
    int nt, int ks, const _Float16* __restrict__ X,
    const _Float16* __restrict__ Wh, float* __restrict__ part,
    _Float16* wl, int tid) {
  constexpr int KW = 64;              // k per stage
  constexpr int TILEH = 64 * KW;      // halves per tile (4096 = 8 KB)
  constexpr int CALLS = 8;            // 1-KB gload_lds per stage
  constexpr int NST = KC / KW;        // stages per block
  static_assert(KC % KW == 0, "geometry");
  const int n0 = nt * 256;
  const int kbeg = ks * KC;
  const int lane = tid & 63;
  const int wave = tid >> 6;
  const int r = lane & 15;
  const int gq = lane >> 4;

  const _Float16* tslice = Wh +
      ((size_t)(n0 / 64 + wave) * (K / KW) + (size_t)(kbeg / KW)) * TILEH +
      (size_t)lane * 8;
  _Float16* lbase0 = wl + (size_t)wave * TILEH;
  _Float16* lbase1 = wl + (size_t)(4 + wave) * TILEH;
  const _Float16* xrow = X + (size_t)r * K + kbeg + 8 * gq;

  f32x4 acc[4][4] = {};  // [mi][ni]

#pragma unroll
  for (int c = 0; c < CALLS; ++c)
    gload_lds16(tslice + c * 512, lbase0 + c * 512);

  for (int st = 0; st < NST; ++st) {
    half8 areg[2][4];
#pragma unroll
    for (int k32 = 0; k32 < 2; ++k32)
#pragma unroll
      for (int mi = 0; mi < 4; ++mi)
        areg[k32][mi] =
            *(const half8*)(xrow + st * KW + k32 * 32 + (size_t)(mi * 16) * K);
    __builtin_amdgcn_sched_barrier(0);
    if (st + 1 < NST) {
      const _Float16* tn = tslice + (size_t)(st + 1) * TILEH;
      _Float16* ln = ((st + 1) & 1) ? lbase1 : lbase0;
#pragma unroll
      for (int c = 0; c < CALLS; ++c)
        gload_lds16(tn + c * 512, ln + c * 512);
      __builtin_amdgcn_sched_barrier(0);
      asm volatile("s_waitcnt vmcnt(%0)" ::"i"(CALLS) : "memory");
    } else {
      asm volatile("s_waitcnt vmcnt(0)" ::: "memory");
    }
    __builtin_amdgcn_sched_barrier(0);
    const char* lcur = (const char*)((st & 1) ? lbase1 : lbase0);
#pragma unroll
    for (int k32 = 0; k32 < 2; ++k32) {
#pragma unroll
      for (int ni = 0; ni < 4; ++ni) {
        const int rr = ni * 16 + r;
        int rbyte = rr * (KW * 2) + (((k32 * 32 + 8 * gq) * 2) ^ ((r & 7) << 4));
        half8 bfv = *(const half8*)(lcur + rbyte);
#pragma unroll
        for (int mi = 0; mi < 4; ++mi)
          acc[mi][ni] = __builtin_amdgcn_mfma_f32_16x16x32_f16(
              areg[k32][mi], bfv, acc[mi][ni], 0, 0, 0);
      }
    }
  }
#pragma unroll
  for (int mi = 0; mi < 4; ++mi) {
#pragma unroll
    for (int ni = 0; ni < 4; ++ni) {
#pragma unroll
      for (int q = 0; q < 4; ++q) {
        int row = mi * 16 + gq * 4 + q;
        int col = n0 + wave * 64 + ni * 16 + r;
        part[((size_t)ks * 64 + row) * N + col] = acc[mi][ni][q];
      }
    }
  }
}

// ---------------- Phase A: scan g[0,384) (blocks 0-63) + full weight convert.
__global__ __launch_bounds__(256) void k_phaseA(
    const _Float16* __restrict__ xproj, const float* __restrict__ h0,
    const float* __restrict__ c0, float* __restrict__ cstate,
    const float* __restrict__ W_hh, _Float16* __restrict__ hs,
    const float* __restrict__ W1, _Float16* __restrict__ W1h,
    const float* __restrict__ W2, _Float16* __restrict__ W2h,
    const float* __restrict__ W3, _Float16* __restrict__ W3h) {
  __shared__ alignas(16) _Float16 hsh[H_];
  const int bid = blockIdx.x;
  if (bid < B_) {
    if (threadIdx.x < 64)
      scan_range<0, GSPLIT, true>(bid, threadIdx.x, xproj, h0, c0, cstate,
                                  W_hh, hs, hsh);
    return;
  }
  const int gtid = (bid - B_) * 256 + threadIdx.x;
  const int gstride = NCONV * 256;
  conv_tiled<5120, 32768>(W1, W1h, gtid, gstride);
  conv_tiled<2560, 5120>(W2, W2h, gtid, gstride);
  conv_tiled<512, 2560>(W3, W3h, gtid, gstride);
}

// ---------------- Phase B: scan g[384,512) (blocks 0-63) + GEMM1 ks 0..23.
__global__ __launch_bounds__(256, 2) void k_phaseB(
    const _Float16* __restrict__ xproj, const float* __restrict__ h0,
    const float* __restrict__ c0, float* __restrict__ cstate,
    const float* __restrict__ W_hh, _Float16* __restrict__ hs,
    const _Float16* __restrict__ W1h, float* __restrict__ part) {
  __shared__ alignas(16) _Float16 wl[8 * 64 * 64];  // 64 KB (2 bufs x 4 waves)
  __shared__ alignas(16) _Float16 hsh[H_];
  const int bid = blockIdx.x;
  if (bid < B_) {
    if (threadIdx.x < 64)
      scan_range<GSPLIT, G_, false>(bid, threadIdx.x, xproj, h0, c0, cstate,
                                    W_hh, hs, hsh);
    return;
  }
  const int b2 = bid - B_;
  gemm_core<5120, 32768, 1024>(b2 % 20, b2 / 20, hs, W1h, part, wl,
                               threadIdx.x);
}

// ---------------- Standalone GEMM (phase C + GEMM2/3): ks = bid/NTILES + off.
template <int N, int K, int KC, int NTILES>
__global__ __launch_bounds__(256, 2) void k_gemm_p(
    const _Float16* __restrict__ X, const _Float16* __restrict__ Wh,
    float* __restrict__ part, int ks_off) {
  static_assert(N == NTILES * 256, "geometry");
  __shared__ alignas(16) _Float16 wl[8 * 64 * 64];  // 64 KB
  const int bid = blockIdx.x;
  gemm_core<N, K, KC>(bid % NTILES, bid / NTILES + ks_off, X, Wh, part, wl,
                      threadIdx.x);
}

// ---------------- reduce k-split partials + bias -> f16 activations (x4 vectorized)
template <int N, int KS>
__global__ __launch_bounds__(256) void k_reduce(
    const float* __restrict__ part, const float* __restrict__ bias,
    _Float16* __restrict__ out) {
  const int idx4 = (blockIdx.x * 256 + threadIdx.x) * 4;
  const int n = idx4 % N;
  f32x4 s = *(const f32x4*)(bias + n);
#pragma unroll
  for (int ks = 0; ks < KS; ++ks) s += *(const f32x4*)(part + (size_t)ks * 64 * N + idx4);
#pragma unroll
  for (int t = 0; t < 4; ++t) out[idx4 + t] = (_Float16)s[t];
}

// ---------------- final reduce + bias + sigmoid -> fp32 output
template <int N, int KS>
__global__ __launch_bounds__(256) void k_reduce_sig(
    const float* __restrict__ part, const float* __restrict__ bias,
    float* __restrict__ out) {
  const int idx4 = (blockIdx.x * 256 + threadIdx.x) * 4;
  const int n = idx4 % N;
  f32x4 s = *(const f32x4*)(bias + n);
#pragma unroll
  for (int ks = 0; ks < KS; ++ks) s += *(const f32x4*)(part + (size_t)ks * 64 * N + idx4);
#pragma unroll
  for (int t = 0; t < 4; ++t) out[idx4 + t] = sigf(s[t]);
}

extern "C" void kernel_launch(void* const* d_in, const int* in_sizes, int n_in,
                              void* d_out, int out_size, void* d_ws, size_t ws_size,
                              hipStream_t stream) {
  const float* input = (const float*)d_in[0];
  const float* h0    = (const float*)d_in[1];
  const float* c0    = (const float*)d_in[2];
  const float* W_ih  = (const float*)d_in[3];
  const float* W_hh  = (const float*)d_in[4];
  const float* b_ih  = (const float*)d_in[5];
  const float* b_hh  = (const float*)d_in[6];
  const float* W1    = (const float*)d_in[7];
  const float* b1    = (const float*)d_in[8];
  const float* W2    = (const float*)d_in[9];
  const float* b2    = (const float*)d_in[10];
  const float* W3    = (const float*)d_in[11];
  const float* b3    = (const float*)d_in[12];
  float* out = (float*)d_out;

  // Workspace layout (DISJOINT regions — part is written in phase B while
  // the scan still reads xproj, so no overlays):
  //   [0,        16777216)   xproj f16 [64][512][256]
  //   [16777216, 20971520)   hs    f16 [64][32768]
  //   [20971520, 21626880)   x2    f16 [64][5120]
  //   [21626880, 21954560)   x3    f16 [64][2560]
  //   [21954560, 21970944)   cstate f32 [64][64]
  //   [22020096, 63963136)   part  f32 (<= 32 x 64 x 5120)
  //   [67108864, 402653184)  W1h f16 tiled
  //   [402653184,428867584)  W2h f16 tiled
  //   [428867584,431489024)  W3h f16 tiled
  uint8_t* ws = (uint8_t*)d_ws;
  _Float16* xproj  = (_Float16*)ws;
  _Float16* hs     = (_Float16*)(ws + 16777216);
  _Float16* x2     = (_Float16*)(ws + 20971520);
  _Float16* x3     = (_Float16*)(ws + 21626880);
  float*    cstate = (float*)(ws + 21954560);
  float*    part   = (float*)(ws + 22020096);
  _Float16* W1h    = (_Float16*)(ws + 67108864);
  _Float16* W2h    = (_Float16*)(ws + 402653184);
  _Float16* W3h    = (_Float16*)(ws + 428867584);

  k_xproj<<<G_, 256, 0, stream>>>(input, W_ih, b_ih, b_hh, xproj);
  // Phase A: scan g<384 (+ c-state save) || full f32->f16 weight convert.
  k_phaseA<<<B_ + NCONV, 256, 0, stream>>>(xproj, h0, c0, cstate, W_hh, hs,
                                           W1, W1h, W2, W2h, W3, W3h);
  // Phase B: scan g>=384 || GEMM1 ks 0..23 (hs for g<384 + W1h ready).
  k_phaseB<<<B_ + 20 * 24, 256, 0, stream>>>(xproj, h0, c0, cstate, W_hh, hs,
                                             W1h, part);
  // Phase C: GEMM1 ks 24..31 (needs the full scan).
  k_gemm_p<5120, 32768, 1024, 20><<<20 * 8, 256, 0, stream>>>(hs, W1h, part, 24);
  k_reduce<5120, 32><<<(64 * 5120) / 4 / 256, 256, 0, stream>>>(part, b1, x2);
  // GEMM2: [64,5120] x W2h[2560,5120]^T, NTILES=10, ksplit=16 (KC=320)
  k_gemm_p<2560, 5120, 320, 10><<<10 * 16, 256, 0, stream>>>(x2, W2h, part, 0);
  k_reduce<2560, 16><<<(64 * 2560) / 4 / 256, 256, 0, stream>>>(part, b2, x3);
  // GEMM3: [64,2560] x W3h[512,2560]^T, NTILES=2, ksplit=10 (KC=256)
  k_gemm_p<512, 2560, 256, 2><<<2 * 10, 256, 0, stream>>>(x3, W3h, part, 0);
  k_reduce_sig<512, 10><<<(64 * 512) / 4 / 256, 256, 0, stream>>>(part, b3, out);
}

// Round 20
// 414.781 us; speedup vs baseline: 1.0484x; 1.0484x over previous
//
#include <hip/hip_runtime.h>
#include <hip/hip_fp16.h>

#define G_ 512
#define B_ 64
#define I_ 32
#define H_ 64
#define NGATE 256  // 4*H

typedef _Float16 half8 __attribute__((ext_vector_type(8)));
typedef _Float16 h4 __attribute__((ext_vector_type(4)));
typedef _Float16 h2 __attribute__((ext_vector_type(2)));
typedef float f32x4 __attribute__((ext_vector_type(4)));

#if __has_builtin(__builtin_amdgcn_fdot2)
#define FDOT2(a, b, c) __builtin_amdgcn_fdot2((a), (b), (c), false)
#else
#define FDOT2(a, b, c) ((c) + (float)(a)[0] * (float)(b)[0] + (float)(a)[1] * (float)(b)[1])
#endif

__device__ __forceinline__ float sigf(float x) {
  return 1.0f / (1.0f + __expf(-x));
}
__device__ __forceinline__ float tanh_fast(float x) {
  x = fminf(fmaxf(x, -15.0f), 15.0f);
  float e = __expf(2.0f * x);
  return (e - 1.0f) / (e + 1.0f);
}

// async global->LDS, 16 B per lane: LDS dest = wave-uniform base, global src
// per-lane (base + lane*16B).
__device__ __forceinline__ void gload_lds16(const _Float16* g, _Float16* l) {
  __builtin_amdgcn_global_load_lds(
      (const __attribute__((address_space(1))) void*)g,
      (__attribute__((address_space(3))) void*)l, 16, 0, 0);
}

// ---------------- K1: xproj[b][g][col*4+q]  (coalesced; scan reads one h4/lane)
__global__ __launch_bounds__(256) void k_xproj(
    const float* __restrict__ input, const float* __restrict__ W_ih,
    const float* __restrict__ b_ih, const float* __restrict__ b_hh,
    _Float16* __restrict__ xproj) {
  const int g = blockIdx.x;
  const int t = threadIdx.x;
  const int col = t >> 2;
  const int q = t & 3;
  const int row = q * H_ + col;  // gate-row in torch i,f,g,o order
  __shared__ alignas(16) float inp[B_ * I_];
  const float* ing = input + (size_t)g * (B_ * I_);
#pragma unroll
  for (int u = 0; u < (B_ * I_) / 256; ++u) inp[u * 256 + t] = ing[u * 256 + t];
  float w[I_];
#pragma unroll
  for (int k = 0; k < I_; k += 4) {
    f32x4 v = *(const f32x4*)(W_ih + (size_t)row * I_ + k);
    w[k] = v[0]; w[k + 1] = v[1]; w[k + 2] = v[2]; w[k + 3] = v[3];
  }
  const float bias = b_ih[row] + b_hh[row];
  __syncthreads();
  for (int b = 0; b < B_; ++b) {
    float a0 = bias, a1 = 0.f, a2 = 0.f, a3 = 0.f;
#pragma unroll
    for (int k = 0; k < I_; k += 4) {
      f32x4 iv = *(const f32x4*)&inp[b * I_ + k];
      a0 += iv[0] * w[k]; a1 += iv[1] * w[k + 1];
      a2 += iv[2] * w[k + 2]; a3 += iv[3] * w[k + 3];
    }
    xproj[((size_t)b * G_ + g) * NGATE + t] = (_Float16)((a0 + a1) + (a2 + a3));
  }
}

// ---------------- R5-proven scan body (barrier-free, depth-8 xproj ring, f16 dots)
__device__ __forceinline__ void scan_row(
    int b, int j, const _Float16* __restrict__ xproj,
    const float* __restrict__ h0, const float* __restrict__ c0,
    const float* __restrict__ W_hh, _Float16* __restrict__ hs,
    _Float16* hsh) {
  h2 w[4][32];
#pragma unroll
  for (int q = 0; q < 4; ++q) {
    const f32x4* wr = (const f32x4*)(W_hh + (size_t)(q * H_ + j) * H_);
#pragma unroll
    for (int kk = 0; kk < 16; ++kk) {
      f32x4 v = wr[kk];
      h2 t0, t1;
      t0[0] = (_Float16)v[0]; t0[1] = (_Float16)v[1];
      t1[0] = (_Float16)v[2]; t1[1] = (_Float16)v[3];
      w[q][2 * kk] = t0;
      w[q][2 * kk + 1] = t1;
    }
  }
  float c = c0[b * H_ + j];
  hsh[j] = (_Float16)h0[b * H_ + j];

  const h4* xrow = (const h4*)(xproj + (size_t)b * G_ * NGATE) + j;
  h4 p[8];
#pragma unroll
  for (int d = 0; d < 8; ++d) p[d] = xrow[(size_t)d * 64];

  _Float16* hrow = hs + (size_t)b * (G_ * H_) + j;

  for (int g0 = 0; g0 < G_; g0 += 8) {
#pragma unroll
    for (int d = 0; d < 8; ++d) {
      const int g = g0 + d;
      float a[4], a2[4];
#pragma unroll
      for (int q = 0; q < 4; ++q) { a[q] = (float)p[d][q]; a2[q] = 0.0f; }
      const f32x4* hp4 = (const f32x4*)hsh;
#pragma unroll
      for (int k4 = 0; k4 < 4; ++k4) {
        f32x4 hv4 = hp4[k4];
#pragma unroll
        for (int t = 0; t < 4; ++t) {
          h2 hv = __builtin_bit_cast(h2, hv4[t]);
#pragma unroll
          for (int q = 0; q < 4; ++q) a[q] = FDOT2(hv, w[q][k4 * 4 + t], a[q]);
        }
      }
#pragma unroll
      for (int k4 = 4; k4 < 8; ++k4) {
        f32x4 hv4 = hp4[k4];
#pragma unroll
        for (int t = 0; t < 4; ++t) {
          h2 hv = __builtin_bit_cast(h2, hv4[t]);
#pragma unroll
          for (int q = 0; q < 4; ++q) a2[q] = FDOT2(hv, w[q][k4 * 4 + t], a2[q]);
        }
      }
#pragma unroll
      for (int q = 0; q < 4; ++q) a[q] += a2[q];

      float ig = sigf(a[0]);
      float fg = sigf(a[1]);
      float gg = tanh_fast(a[2]);
      float og = sigf(a[3]);
      c = fg * c + ig * gg;
      float hh = og * tanh_fast(c);
      _Float16 hf = (_Float16)hh;
      hsh[j] = hf;
      hrow[(size_t)g * H_] = hf;
      if (g + 8 < G_) p[d] = xrow[(size_t)(g + 8) * 64];
    }
  }
}

// ---------------- f32 -> f16 convert into TILE-LINEAR layout, KWT=64 (R15-proven).
template <int N, int K>
__device__ __forceinline__ void conv_tiled(
    const float* __restrict__ src, _Float16* __restrict__ dst,
    int gtid, int gstride) {
  constexpr int KWT = 64;
  constexpr int TILEH = 64 * KWT;  // halves per tile (4096)
  for (int i = gtid; i < N * (K / 8); i += gstride) {
    const int n = i / (K / 8);
    const int k8 = i % (K / 8);
    const f32x4* s = (const f32x4*)(src + (size_t)n * K + (size_t)k8 * 8);
    f32x4 v0 = s[0];
    f32x4 v1 = s[1];
    half8 h;
    h[0] = (_Float16)v0[0]; h[1] = (_Float16)v0[1];
    h[2] = (_Float16)v0[2]; h[3] = (_Float16)v0[3];
    h[4] = (_Float16)v1[0]; h[5] = (_Float16)v1[1];
    h[6] = (_Float16)v1[2]; h[7] = (_Float16)v1[3];
    const int nt = n >> 6, rr = n & 63;
    const int ksg = k8 >> 3;         // k/64
    const int kk8 = k8 & 7;          // (k%64)/8
    const size_t tile_id = (size_t)nt * (K / KWT) + ksg;
    int byte = rr * (KWT * 2) + ((kk8 * 16) ^ ((rr & 7) << 4));
    *(half8*)((char*)(dst + tile_id * TILEH) + byte) = h;
  }
}

#define NCONV 2048

// ---------------- K2: fused scan (blocks 0-63) + tiled weight convert (blocks 64+)
__global__ __launch_bounds__(256) void k_scan_conv(
    const _Float16* __restrict__ xproj, const float* __restrict__ h0,
    const float* __restrict__ c0, const float* __restrict__ W_hh,
    _Float16* __restrict__ hs,
    const float* __restrict__ W1, _Float16* __restrict__ W1h,
    const float* __restrict__ W2, _Float16* __restrict__ W2h,
    const float* __restrict__ W3, _Float16* __restrict__ W3h) {
  __shared__ alignas(16) _Float16 hsh[H_];
  const int bid = blockIdx.x;
  if (bid < B_) {
    if (threadIdx.x < 64)
      scan_row(bid, threadIdx.x, xproj, h0, c0, W_hh, hs, hsh);
    return;
  }
  const int gtid = (bid - B_) * 256 + threadIdx.x;
  const int gstride = NCONV * 256;
  conv_tiled<5120, 32768>(W1, W1h, gtid, gstride);
  conv_tiled<2560, 5120>(W2, W2h, gtid, gstride);
  conv_tiled<512, 2560>(W3, W3h, gtid, gstride);
}

// ---------------- PIPELINED barrier-free GEMM, 256-wide n-blocks (R15-proven).
template <int N, int K, int KC, int NTILES, int KSPLIT>
__global__ __launch_bounds__(256, 2) void k_gemm_p(
    const _Float16* __restrict__ X, const _Float16* __restrict__ Wh,
    float* __restrict__ part) {
  constexpr int KW = 64;              // k per stage
  constexpr int TILEH = 64 * KW;      // halves per tile (4096 = 8 KB)
  constexpr int CALLS = 8;            // 1-KB gload_lds per stage (8 KB)
  constexpr int NST = KC / KW;        // stages per block
  static_assert(KC % KW == 0 && N == NTILES * 256, "geometry");
  __shared__ alignas(16) _Float16 wl[2][4][TILEH];  // 64 KB
  const int bid = blockIdx.x;
  const int nt = bid % NTILES;
  const int ks = bid / NTILES;
  const int n0 = nt * 256;
  const int kbeg = ks * KC;
  const int lane = threadIdx.x & 63;
  const int wave = threadIdx.x >> 6;
  const int r = lane & 15;
  const int gq = lane >> 4;

  const _Float16* tslice = Wh +
      ((size_t)(n0 / 64 + wave) * (K / KW) + (size_t)(kbeg / KW)) * TILEH +
      (size_t)lane * 8;
  _Float16* lbase0 = &wl[0][wave][0];
  _Float16* lbase1 = &wl[1][wave][0];
  const _Float16* xrow = X + (size_t)r * K + kbeg + 8 * gq;

  f32x4 acc[4][4] = {};  // [mi][ni]

  // prologue: stage 0 into buf 0
#pragma unroll
  for (int c = 0; c < CALLS; ++c)
    gload_lds16(tslice + c * 512, lbase0 + c * 512);

  for (int st = 0; st < NST; ++st) {
    half8 areg[2][4];
#pragma unroll
    for (int k32 = 0; k32 < 2; ++k32)
#pragma unroll
      for (int mi = 0; mi < 4; ++mi)
        areg[k32][mi] =
            *(const half8*)(xrow + st * KW + k32 * 32 + (size_t)(mi * 16) * K);
    __builtin_amdgcn_sched_barrier(0);
    if (st + 1 < NST) {
      const _Float16* tn = tslice + (size_t)(st + 1) * TILEH;
      _Float16* ln = ((st + 1) & 1) ? lbase1 : lbase0;
#pragma unroll
      for (int c = 0; c < CALLS; ++c)
        gload_lds16(tn + c * 512, ln + c * 512);
      __builtin_amdgcn_sched_barrier(0);
      asm volatile("s_waitcnt vmcnt(%0)" ::"i"(CALLS) : "memory");
    } else {
      asm volatile("s_waitcnt vmcnt(0)" ::: "memory");
    }
    __builtin_amdgcn_sched_barrier(0);
    const char* lcur = (const char*)((st & 1) ? lbase1 : lbase0);
#pragma unroll
    for (int k32 = 0; k32 < 2; ++k32) {
#pragma unroll
      for (int ni = 0; ni < 4; ++ni) {
        const int rr = ni * 16 + r;
        int rbyte = rr * (KW * 2) + (((k32 * 32 + 8 * gq) * 2) ^ ((r & 7) << 4));
        half8 bfv = *(const half8*)(lcur + rbyte);
#pragma unroll
        for (int mi = 0; mi < 4; ++mi)
          acc[mi][ni] = __builtin_amdgcn_mfma_f32_16x16x32_f16(
              areg[k32][mi], bfv, acc[mi][ni], 0, 0, 0);
      }
    }
  }
#pragma unroll
  for (int mi = 0; mi < 4; ++mi) {
#pragma unroll
    for (int ni = 0; ni < 4; ++ni) {
#pragma unroll
      for (int q = 0; q < 4; ++q) {
        int row = mi * 16 + gq * 4 + q;
        int col = n0 + wave * 64 + ni * 16 + r;
        part[((size_t)ks * 64 + row) * N + col] = acc[mi][ni][q];
      }
    }
  }
}

// ---------------- reduce k-split partials + bias -> f16 activations (x4 vectorized)
template <int N, int KS>
__global__ __launch_bounds__(256) void k_reduce(
    const float* __restrict__ part, const float* __restrict__ bias,
    _Float16* __restrict__ out) {
  const int idx4 = (blockIdx.x * 256 + threadIdx.x) * 4;
  const int n = idx4 % N;
  f32x4 s = *(const f32x4*)(bias + n);
#pragma unroll
  for (int ks = 0; ks < KS; ++ks) s += *(const f32x4*)(part + (size_t)ks * 64 * N + idx4);
#pragma unroll
  for (int t = 0; t < 4; ++t) out[idx4 + t] = (_Float16)s[t];
}

// ---------------- final reduce + bias + sigmoid -> fp32 output
template <int N, int KS>
__global__ __launch_bounds__(256) void k_reduce_sig(
    const float* __restrict__ part, const float* __restrict__ bias,
    float* __restrict__ out) {
  const int idx4 = (blockIdx.x * 256 + threadIdx.x) * 4;
  const int n = idx4 % N;
  f32x4 s = *(const f32x4*)(bias + n);
#pragma unroll
  for (int ks = 0; ks < KS; ++ks) s += *(const f32x4*)(part + (size_t)ks * 64 * N + idx4);
#pragma unroll
  for (int t = 0; t < 4; ++t) out[idx4 + t] = sigf(s[t]);
}

extern "C" void kernel_launch(void* const* d_in, const int* in_sizes, int n_in,
                              void* d_out, int out_size, void* d_ws, size_t ws_size,
                              hipStream_t stream) {
  const float* input = (const float*)d_in[0];
  const float* h0    = (const float*)d_in[1];
  const float* c0    = (const float*)d_in[2];
  const float* W_ih  = (const float*)d_in[3];
  const float* W_hh  = (const float*)d_in[4];
  const float* b_ih  = (const float*)d_in[5];
  const float* b_hh  = (const float*)d_in[6];
  const float* W1    = (const float*)d_in[7];
  const float* b1    = (const float*)d_in[8];
  const float* W2    = (const float*)d_in[9];
  const float* b2    = (const float*)d_in[10];
  const float* W3    = (const float*)d_in[11];
  const float* b3    = (const float*)d_in[12];
  float* out = (float*)d_out;

  // Workspace layout (~411.5 MB of ~2.6 GB): see R11.
  uint8_t* ws = (uint8_t*)d_ws;
  float*    part  = (float*)ws;
  _Float16* xproj = (_Float16*)ws;
  _Float16* hs    = (_Float16*)(ws + 41943040);
  _Float16* x2    = (_Float16*)(ws + 46137344);
  _Float16* x3    = (_Float16*)(ws + 46792704);
  _Float16* W1h   = (_Float16*)(ws + 47120384);
  _Float16* W2h   = (_Float16*)(ws + 382664704);
  _Float16* W3h   = (_Float16*)(ws + 408879104);

  k_xproj<<<G_, 256, 0, stream>>>(input, W_ih, b_ih, b_hh, xproj);
  k_scan_conv<<<B_ + NCONV, 256, 0, stream>>>(xproj, h0, c0, W_hh, hs,
                                              W1, W1h, W2, W2h, W3, W3h);
  // GEMM1: [64,32768] x W1h[5120,32768]^T, NTILES=20 (n-block 256), ksplit=32
  k_gemm_p<5120, 32768, 1024, 20, 32><<<20 * 32, 256, 0, stream>>>(hs, W1h, part);
  k_reduce<5120, 32><<<(64 * 5120) / 4 / 256, 256, 0, stream>>>(part, b1, x2);
  // GEMM2: [64,5120] x W2h[2560,5120]^T, NTILES=10, ksplit=16 (KC=320, 5 stages)
  k_gemm_p<2560, 5120, 320, 10, 16><<<10 * 16, 256, 0, stream>>>(x2, W2h, part);
  k_reduce<2560, 16><<<(64 * 2560) / 4 / 256, 256, 0, stream>>>(part, b2, x3);
  // GEMM3: [64,2560] x W3h[512,2560]^T, NTILES=2, ksplit=10 (KC=256, 4 stages)
  k_gemm_p<512, 2560, 256, 2, 10><<<2 * 10, 256, 0, stream>>>(x3, W3h, part);
  k_reduce_sig<512, 10><<<(64 * 512) / 4 / 256, 256, 0, stream>>>(part, b3, out);
}